// Round 14
// baseline (104.618 us; speedup 1.0000x reference)
//
#include <hip/hip_runtime.h>
#include <hip/hip_bf16.h>

// AttentivePooling: B=32, S=8192, C=256, MID=128, fp32 in/out.
// out[b,c] = sum_s softmax_s( tanh(x@W1+b1)@w2 )[b,s] * x[b,s,c]   (b2 shift-invariant)
//
// R14: R13 skeleton + depth-2 DMA pipeline. 3-slot LDS ring (A,B), ONE barrier
// per chunk: { vmcnt(4); s_barrier; STAGE(k+2); compute(k) }. The DMA queue
// holds 16-32KB per block at every instant incl. the wait point (R13 dropped
// to one queued chunk at its wait). 53KB LDS -> 3 blocks/CU, 12 waves/CU.

typedef __attribute__((ext_vector_type(8))) short short8;
typedef __attribute__((ext_vector_type(4))) float f32x4;
typedef unsigned short u16;

constexpr int Bb = 32;
constexpr int Ss = 8192;
constexpr int Cc = 256;
constexpr int MIDm = 128;
constexpr int BM = 64;               // rows per block
constexpr int BK = 32;               // fp32 cols per chunk
constexpr int NCH = Cc / BK;         // 8 chunks
constexpr int NBLK = Bb * Ss / BM;   // 4096
constexpr int BPB = Ss / BM;         // 128 partials per batch

__device__ __forceinline__ u16 f2bf(float f) {
  return __builtin_bit_cast(u16, __float2bfloat16(f));   // RNE
}

// ---- one-time prep: W fragments, frag-major (identical to R13) ----
// t = wc*2048 + kcc*256 + nt*64 + lane  -> 8 bf16 (16B):
//   n = wc*64 + nt*16 + (lane&15),  k = kcc*32 + (lane>>4)*8 + e
__global__ __launch_bounds__(256) void wprep_kernel(
    const float* __restrict__ W1, u16* __restrict__ FB)
{
  const int t    = blockIdx.x * 256 + threadIdx.x;   // 0..4095
  const int lane = t & 63;
  const int nt   = (t >> 6) & 3;
  const int kcc  = (t >> 8) & 7;
  const int wc   = (t >> 11) & 1;
  const int n    = wc * 64 + nt * 16 + (lane & 15);
  const int k0   = kcc * 32 + (lane >> 4) * 8;
  union { u16 v[8]; short8 s; } u;
  #pragma unroll
  for (int e = 0; e < 8; ++e) u.v[e] = f2bf(W1[(size_t)(k0 + e) * MIDm + n]);
  *(short8*)(FB + (size_t)t * 8) = u.s;
}

// ---- fused: depth-2 counted-vmcnt DMA ring -> MFMA -> softmax -> weighted x ----
__global__ __launch_bounds__(256, 3) void fused_kernel(
    const float* __restrict__ x, const u16* __restrict__ FB,
    const float* __restrict__ b1, const float* __restrict__ w2,
    float* __restrict__ oPart, float* __restrict__ mPart, float* __restrict__ lPart)
{
  __shared__ __align__(16) char sXA[3][8192];   // A ring: 64 rows x 128B, swizzled
  __shared__ __align__(16) char sB[3][8192];    // B ring: 2 wc x 4KB frag-major
  __shared__ float sScore[2][BM];
  __shared__ float sP[BM];
  __shared__ float sO[4][Cc];
  __shared__ float sML[2];

  const int tid  = threadIdx.x;
  const int lane = tid & 63;
  const int w    = tid >> 6;
  const int wr   = w >> 1;          // row half (rows wr*32 .. +32)
  const int wc   = w & 1;           // col half (cols wc*64 .. +64)
  const int q    = lane >> 4;
  const int ln   = lane & 15;
  const int row0 = blockIdx.x * BM;

  // acc init with b1[col]: 2 mt x 4 nt
  f32x4 acc[2][4];
  #pragma unroll
  for (int nt = 0; nt < 4; ++nt) {
    float bj = b1[wc * 64 + nt * 16 + ln];
    #pragma unroll
    for (int mt = 0; mt < 2; ++mt) {
      acc[mt][nt][0] = bj; acc[mt][nt][1] = bj; acc[mt][nt][2] = bj; acc[mt][nt][3] = bj;
    }
  }

  // STAGE chunk kc into ring slot sl: 2 A-DMA + 2 B-DMA per thread (4 insts).
  // A: LDS byte L (row=L>>7, cb=L&127) holds global col byte cb^((row&7)<<4).
  #define STAGE_ALL(sl, kc)                                                           \
    {                                                                                 \
      _Pragma("unroll")                                                               \
      for (int r = 0; r < 2; ++r) {                                                   \
        int L   = r * 4096 + tid * 16;                                                \
        int row = L >> 7;                                                             \
        int cb  = (L & 127) ^ ((row & 7) << 4);                                       \
        const char* src = (const char*)x                                              \
            + ((size_t)(row0 + row) * Cc + (size_t)(kc) * BK) * 4 + cb;               \
        __builtin_amdgcn_global_load_lds(                                             \
            (const __attribute__((address_space(1))) void*)src,                       \
            (__attribute__((address_space(3))) void*)(&sXA[sl][0] + L),               \
            16, 0, 0);                                                                \
      }                                                                               \
      _Pragma("unroll")                                                               \
      for (int r = 0; r < 2; ++r) {                                                   \
        const char* srcb = (const char*)FB                                            \
            + ((size_t)r * 2048 + (size_t)(kc) * 256) * 16 + (size_t)tid * 16;        \
        __builtin_amdgcn_global_load_lds(                                             \
            (const __attribute__((address_space(1))) void*)srcb,                      \
            (__attribute__((address_space(3))) void*)(&sB[sl][0] + r * 4096 + tid * 16),\
            16, 0, 0);                                                                \
      }                                                                               \
    }

  // prologue: chunks 0 and 1 in flight
  STAGE_ALL(0, 0);
  STAGE_ALL(1, 1);

  #pragma unroll
  for (int kc = 0; kc < NCH; ++kc) {
    const int cur = kc % 3;

    __builtin_amdgcn_sched_barrier(0);
    if (kc < NCH - 1) asm volatile("s_waitcnt vmcnt(4)" ::: "memory");  // kc landed; kc+1 flying
    else              asm volatile("s_waitcnt vmcnt(0)" ::: "memory");
    __builtin_amdgcn_sched_barrier(0);
    __builtin_amdgcn_s_barrier();      // chunk kc visible AND compute(kc-1) done block-wide
    __builtin_amdgcn_sched_barrier(0);

    if (kc + 2 < NCH) STAGE_ALL((kc + 2) % 3, kc + 2);   // keep queue at 2 chunks deep

    // B fragments for this wave's column half
    const char* bb = &sB[cur][0] + wc * 4096 + lane * 16;
    short8 bfrag[4];
    #pragma unroll
    for (int nt = 0; nt < 4; ++nt)
      bfrag[nt] = *(const short8*)(bb + nt * 1024);

    // A fragments (swizzled read) + cvt + MFMA
    #pragma unroll
    for (int mt = 0; mt < 2; ++mt) {
      const int row = 32 * wr + 16 * mt + ln;
      const int s   = (row & 7) << 4;
      const char* base = &sXA[cur][0] + row * 128;
      float4 lo = *(const float4*)(base + ((q * 32) ^ s));
      float4 hi = *(const float4*)(base + ((q * 32 + 16) ^ s));
      union { u16 v[8]; short8 s8; } t8;
      t8.v[0] = f2bf(lo.x); t8.v[1] = f2bf(lo.y); t8.v[2] = f2bf(lo.z); t8.v[3] = f2bf(lo.w);
      t8.v[4] = f2bf(hi.x); t8.v[5] = f2bf(hi.y); t8.v[6] = f2bf(hi.z); t8.v[7] = f2bf(hi.w);
      #pragma unroll
      for (int nt = 0; nt < 4; ++nt)
        acc[mt][nt] = __builtin_amdgcn_mfma_f32_16x16x32_bf16(
            t8.s8, bfrag[nt], acc[mt][nt], 0, 0, 0);
    }
    // no bottom barrier: next iteration's top barrier provides the guarantee
  }

  // ---- epilogue: score[r] = sum_col tanh(h)*w2[col] ----
  float w2v[4];
  #pragma unroll
  for (int nt = 0; nt < 4; ++nt) w2v[nt] = w2[wc * 64 + nt * 16 + ln];

  float p[2][4];
  #pragma unroll
  for (int mt = 0; mt < 2; ++mt)
    #pragma unroll
    for (int r = 0; r < 4; ++r) p[mt][r] = 0.f;

  #pragma unroll
  for (int mt = 0; mt < 2; ++mt)
    #pragma unroll
    for (int nt = 0; nt < 4; ++nt)
      #pragma unroll
      for (int r = 0; r < 4; ++r)
        p[mt][r] += (1.0f - 2.0f / (__expf(2.0f * acc[mt][nt][r]) + 1.0f)) * w2v[nt];

  #pragma unroll
  for (int off = 1; off < 16; off <<= 1)
    #pragma unroll
    for (int mt = 0; mt < 2; ++mt)
      #pragma unroll
      for (int r = 0; r < 4; ++r)
        p[mt][r] += __shfl_xor(p[mt][r], off);

  if (ln == 0) {
    #pragma unroll
    for (int mt = 0; mt < 2; ++mt)
      #pragma unroll
      for (int r = 0; r < 4; ++r)
        sScore[wc][32 * wr + 16 * mt + 4 * q + r] = p[mt][r];
  }
  __syncthreads();

  // ---- block softmax over 64 rows (wave 0) ----
  if (tid < BM) sP[tid] = sScore[0][tid] + sScore[1][tid];
  __syncthreads();
  if (w == 0) {
    float v = sP[lane];
    float m = v;
    #pragma unroll
    for (int off = 1; off < 64; off <<= 1) m = fmaxf(m, __shfl_xor(m, off));
    float e = __expf(v - m);
    float s = e;
    #pragma unroll
    for (int off = 1; off < 64; off <<= 1) s += __shfl_xor(s, off);
    sP[lane] = e;
    if (lane == 0) { sML[0] = m; sML[1] = s; }
  }
  __syncthreads();

  // ---- weighted x partial: wave w covers rows w*16..+16 (L2/L3-hot re-read) ----
  const float* xo = x + (size_t)(row0 + w * 16) * Cc + lane * 4;
  float4 o = make_float4(0.f, 0.f, 0.f, 0.f);
  #pragma unroll 8
  for (int r = 0; r < 16; ++r) {
    float pw = sP[w * 16 + r];
    float4 xv = *(const float4*)(xo + (size_t)r * Cc);
    o.x = fmaf(pw, xv.x, o.x);
    o.y = fmaf(pw, xv.y, o.y);
    o.z = fmaf(pw, xv.z, o.z);
    o.w = fmaf(pw, xv.w, o.w);
  }
  *(float4*)&sO[w][lane * 4] = o;
  __syncthreads();

  oPart[(size_t)blockIdx.x * Cc + tid] =
      sO[0][tid] + sO[1][tid] + sO[2][tid] + sO[3][tid];
  if (tid == 0) { mPart[blockIdx.x] = sML[0]; lPart[blockIdx.x] = sML[1]; }
}

// ---- combine 128 block-partials per batch (parallel, deterministic) ----
__global__ __launch_bounds__(256) void combine_kernel(
    const float* __restrict__ oPart, const float* __restrict__ mPart,
    const float* __restrict__ lPart, float* __restrict__ out)
{
  const int b   = blockIdx.x >> 3;
  const int cg  = blockIdx.x & 7;
  const int kk  = threadIdx.x >> 5;   // 0..7
  const int c   = threadIdx.x & 31;
  const int col = cg * 32 + c;

  float M = -3.4e38f;
  for (int k = 0; k < BPB; ++k) M = fmaxf(M, mPart[b * BPB + k]);
  float den = 0.f;
  for (int k = 0; k < BPB; ++k)
    den += __expf(mPart[b * BPB + k] - M) * lPart[b * BPB + k];

  float num = 0.f;
  #pragma unroll 4
  for (int j = 0; j < BPB / 8; ++j) {
    const int k = j * 8 + kk;
    float wgt = __expf(mPart[b * BPB + k] - M);
    num = fmaf(wgt, oPart[(size_t)(b * BPB + k) * Cc + col], num);
  }
  __shared__ float red[8][32];
  red[kk][c] = num;
  __syncthreads();
  if (kk == 0) {
    float s = 0.f;
    #pragma unroll
    for (int i = 0; i < 8; ++i) s += red[i][c];
    out[b * Cc + col] = s / den;
  }
}

extern "C" void kernel_launch(void* const* d_in, const int* in_sizes, int n_in,
                              void* d_out, int out_size, void* d_ws, size_t ws_size,
                              hipStream_t stream)
{
  const float* x  = (const float*)d_in[0];
  const float* W1 = (const float*)d_in[1];
  const float* b1 = (const float*)d_in[2];
  const float* w2 = (const float*)d_in[3];
  // d_in[4] = b2: unused (softmax shift-invariant)
  float* out = (float*)d_out;

  u16*   FB    = (u16*)d_ws;                                        // 64 KB
  float* oPart = (float*)((char*)d_ws + 65536);                     // 4 MB (4096x256)
  float* mPart = (float*)((char*)d_ws + 65536 + 4194304);           // 16 KB
  float* lPart = (float*)((char*)d_ws + 65536 + 4194304 + 16384);   // 16 KB

  wprep_kernel<<<16, 256, 0, stream>>>(W1, FB);
  fused_kernel<<<NBLK, 256, 0, stream>>>(x, FB, b1, w2, oPart, mPart, lPart);
  combine_kernel<<<Bb * 8, 256, 0, stream>>>(oPart, mPart, lPart, out);
}